// Round 19
// baseline (4679.582 us; speedup 1.0000x reference)
//
#include <hip/hip_runtime.h>

// VectorQuantizer: B=32768, K=8192, D=256, fp32.
// out layout (flat float): z_q [B*D], vq_loss [1], commit [1], indices-as-float [B]
// ws layout: ebf bf16[K*D] (4MB) | sz float[B] | partial float[B/4]
//
// Strategy (round 19): two-phase MFMA candidate filter + exact fp32 verify.
//  B1: bf16 MFMA GEMM-max -> rowmax of approx dot per row (written to idx_f slot).
//  B2: re-scan, emit codes with dot >= rowmax - M(row) into per-row buffer
//      (first 16 ints of the row's zq area).  M = 4e-5 + 3.2e-5*||z|| is 2x the
//      rigorous error bound (bf16 RNE rel-err 2^-9, ||e|| <= 16/8192, accum eps).
//  C:  exact fp32 FMA chain (ascending d, bit-identical to verified r2 numerics)
//      over candidates; first-index ties; fused gather/zq/loss. cnt>15 or ==0 ->
//      full exact scan fallback.
// MFMA fragments (16x16x32 bf16): A row=lane&15, k=(lane>>4)*8+i; B col=lane&15,
// same k map; C/D col=lane&15, row=(lane>>4)*4+reg [m89-verified family].

namespace {
constexpr int NB = 32768;
constexpr int NK = 8192;
constexpr int ND = 256;

typedef __attribute__((ext_vector_type(8))) short sh8;
typedef __attribute__((ext_vector_type(4))) float f32x4;

__device__ __forceinline__ unsigned short bf16_rne(float f) {
  unsigned int u = __float_as_uint(f);
  u += 0x7FFFu + ((u >> 16) & 1u);
  return (unsigned short)(u >> 16);
}

// ---- S[row] = ||z_row||^2 ----
__global__ void sz_kernel(const float* __restrict__ z, float* __restrict__ sz) {
  const int row = blockIdx.x * 4 + (threadIdx.x >> 6);
  const int lane = threadIdx.x & 63;
  const float4 v = reinterpret_cast<const float4*>(z)[(size_t)row * 64 + lane];
  float s = v.x * v.x + v.y * v.y + v.z * v.z + v.w * v.w;
#pragma unroll
  for (int off = 32; off; off >>= 1) s += __shfl_down(s, off, 64);
  if (lane == 0) sz[row] = s;
}

// ---- emb -> bf16 (RNE) ----
__global__ void ebf_kernel(const float* __restrict__ emb,
                           unsigned short* __restrict__ ebf) {
  const int i = blockIdx.x * 256 + threadIdx.x;  // 8 elems per thread
  const float4 a = reinterpret_cast<const float4*>(emb)[i * 2];
  const float4 b = reinterpret_cast<const float4*>(emb)[i * 2 + 1];
  uint4 o;
  o.x = (unsigned)bf16_rne(a.x) | ((unsigned)bf16_rne(a.y) << 16);
  o.y = (unsigned)bf16_rne(a.z) | ((unsigned)bf16_rne(a.w) << 16);
  o.z = (unsigned)bf16_rne(b.x) | ((unsigned)bf16_rne(b.y) << 16);
  o.w = (unsigned)bf16_rne(b.z) | ((unsigned)bf16_rne(b.w) << 16);
  reinterpret_cast<uint4*>(ebf)[i] = o;
}

// ---- MFMA scan: PASS 0 = rowmax, PASS 1 = candidate emission ----
template <int PASS>
__global__ __launch_bounds__(256, 1) void mfma_scan(
    const float* __restrict__ z, const unsigned short* __restrict__ ebf,
    const float* __restrict__ sz, float* __restrict__ rowmax,
    float* __restrict__ zqout) {
  const int lane = threadIdx.x & 63;
  const int w = threadIdx.x >> 6;
  const int r0 = blockIdx.x * 64 + w * 16;  // this wave's 16 rows
  const int cl = lane & 15;                 // A-row / B-col slot
  const int kg = lane >> 4;                 // k-group (0..3)

  // A fragments: rows r0+cl, k = q*32 + kg*8 + i  (bf16 on the fly)
  sh8 afrag[8];
  {
    const float* zp = z + (size_t)(r0 + cl) * ND + kg * 8;
#pragma unroll
    for (int q = 0; q < 8; ++q) {
      const float4 f0 = *reinterpret_cast<const float4*>(zp + q * 32);
      const float4 f1 = *reinterpret_cast<const float4*>(zp + q * 32 + 4);
      sh8 a;
      a[0] = (short)bf16_rne(f0.x); a[1] = (short)bf16_rne(f0.y);
      a[2] = (short)bf16_rne(f0.z); a[3] = (short)bf16_rne(f0.w);
      a[4] = (short)bf16_rne(f1.x); a[5] = (short)bf16_rne(f1.y);
      a[6] = (short)bf16_rne(f1.z); a[7] = (short)bf16_rne(f1.w);
      afrag[q] = a;
    }
  }

  float mx[4] = {-3.4e38f, -3.4e38f, -3.4e38f, -3.4e38f};
  float thr[4];
  if (PASS == 1) {
#pragma unroll
    for (int r = 0; r < 4; ++r) {
      const int row = r0 + kg * 4 + r;
      thr[r] = rowmax[row] - (4e-5f + 3.2e-5f * sqrtf(sz[row]));
    }
  }

  const unsigned short* bbase = ebf + kg * 8 + (size_t)cl * ND;
  auto loadB = [&](sh8* dst, int c0t) {
    const unsigned short* bp = bbase + (size_t)c0t * ND;
#pragma unroll
    for (int q = 0; q < 8; ++q)
      dst[q] = *reinterpret_cast<const sh8*>(bp + q * 32);
  };

  auto process = [&](const sh8* b, int t) {
    f32x4 c0 = {0.f, 0.f, 0.f, 0.f}, c1 = c0, c2 = c0, c3 = c0;
    c0 = __builtin_amdgcn_mfma_f32_16x16x32_bf16(afrag[0], b[0], c0, 0, 0, 0);
    c1 = __builtin_amdgcn_mfma_f32_16x16x32_bf16(afrag[1], b[1], c1, 0, 0, 0);
    c2 = __builtin_amdgcn_mfma_f32_16x16x32_bf16(afrag[2], b[2], c2, 0, 0, 0);
    c3 = __builtin_amdgcn_mfma_f32_16x16x32_bf16(afrag[3], b[3], c3, 0, 0, 0);
    c0 = __builtin_amdgcn_mfma_f32_16x16x32_bf16(afrag[4], b[4], c0, 0, 0, 0);
    c1 = __builtin_amdgcn_mfma_f32_16x16x32_bf16(afrag[5], b[5], c1, 0, 0, 0);
    c2 = __builtin_amdgcn_mfma_f32_16x16x32_bf16(afrag[6], b[6], c2, 0, 0, 0);
    c3 = __builtin_amdgcn_mfma_f32_16x16x32_bf16(afrag[7], b[7], c3, 0, 0, 0);
    const f32x4 dot = (c0 + c1) + (c2 + c3);
    if (PASS == 0) {
#pragma unroll
      for (int r = 0; r < 4; ++r) mx[r] = fmaxf(mx[r], dot[r]);
    } else {
#pragma unroll
      for (int r = 0; r < 4; ++r) {
        if (dot[r] >= thr[r]) {
          const int row = r0 + kg * 4 + r;
          const int code = t * 16 + cl;
          int* cp = (int*)(zqout + (size_t)row * ND);
          const int slot = atomicAdd(cp, 1);
          if (slot < 15) cp[1 + slot] = code;
        }
      }
    }
  };

  sh8 bA[8], bB[8];
  loadB(bA, 0);
  for (int t = 0; t < NK / 16; t += 2) {  // 512 tiles, ping-pong unrolled
    loadB(bB, (t + 1) * 16);
    process(bA, t);
    if (t + 2 < NK / 16) loadB(bA, (t + 2) * 16);
    process(bB, t + 1);
  }

  if (PASS == 0) {
    // reduce max across the 16 col-lanes of each kg group
#pragma unroll
    for (int r = 0; r < 4; ++r) {
      float v = mx[r];
#pragma unroll
      for (int m = 1; m < 16; m <<= 1) v = fmaxf(v, __shfl_xor(v, m, 64));
      if (cl == 0) rowmax[r0 + kg * 4 + r] = v;
    }
    // zero candidate counters for this block's 64 rows
    if (threadIdx.x < 64)
      ((int*)(zqout + (size_t)(blockIdx.x * 64 + threadIdx.x) * ND))[0] = 0;
  }
}

// ---- exact verify + gather + loss partial (4 rows per block) ----
__global__ __launch_bounds__(256, 1) void exact_kernel(
    const float* __restrict__ z, const float* __restrict__ emb,
    const float* __restrict__ sz, float* __restrict__ zq,
    float* __restrict__ idx_f, float* __restrict__ partial) {
  __shared__ float wps[4];
  const int lane = threadIdx.x & 63;
  const int w = threadIdx.x >> 6;
  const int row = blockIdx.x * 4 + w;
  int* cp = (int*)(zq + (size_t)row * ND);
  const int cnt = cp[0];
  const float S = sz[row];
  const float4* zp = reinterpret_cast<const float4*>(z + (size_t)row * ND);

  float bd = 3.4e38f;
  int bc = 0x7fffffff;
  if (cnt >= 1 && cnt <= 15) {
    if (lane < cnt) {
      const int k = cp[1 + lane];
      const float4* ep = reinterpret_cast<const float4*>(emb + (size_t)k * ND);
      float acc = 0.f;
#pragma unroll 8
      for (int q = 0; q < 64; ++q) {  // exact chain, ascending d
        const float4 zz = zp[q];
        const float4 ee = ep[q];
        acc = fmaf(zz.x, ee.x, acc);
        acc = fmaf(zz.y, ee.y, acc);
        acc = fmaf(zz.z, ee.z, acc);
        acc = fmaf(zz.w, ee.w, acc);
      }
      bd = fmaf(-2.f, acc, S);
      bc = k;
    }
  } else {
    // fallback: full exact scan (overflow or empty — correctness net)
    for (int code = lane; code < NK; code += 64) {
      const float4* ep = reinterpret_cast<const float4*>(emb + (size_t)code * ND);
      float acc = 0.f;
#pragma unroll 8
      for (int q = 0; q < 64; ++q) {
        const float4 zz = zp[q];
        const float4 ee = ep[q];
        acc = fmaf(zz.x, ee.x, acc);
        acc = fmaf(zz.y, ee.y, acc);
        acc = fmaf(zz.z, ee.z, acc);
        acc = fmaf(zz.w, ee.w, acc);
      }
      const float dist = fmaf(-2.f, acc, S);
      if (dist < bd || (dist == bd && code < bc)) { bd = dist; bc = code; }
    }
  }
  // min-reduce across 64 lanes; lowest code on exact ties
#pragma unroll
  for (int m = 1; m < 64; m <<= 1) {
    const float od = __shfl_xor(bd, m, 64);
    const int oc = __shfl_xor(bc, m, 64);
    if (od < bd || (od == bd && oc < bc)) { bd = od; bc = oc; }
  }
  // fused gather (reads of cp finished above; safe to overwrite)
  const float4 e = reinterpret_cast<const float4*>(emb)[(size_t)bc * 64 + lane];
  const float4 zv = zp[lane];
  reinterpret_cast<float4*>(zq)[(size_t)row * 64 + lane] = e;
  const float dx = e.x - zv.x, dy = e.y - zv.y;
  const float dz = e.z - zv.z, dw = e.w - zv.w;
  float s = dx * dx + dy * dy + dz * dz + dw * dw;
#pragma unroll
  for (int off = 32; off; off >>= 1) s += __shfl_down(s, off, 64);
  if (lane == 0) {
    idx_f[row] = (float)bc;
    wps[w] = s;
  }
  __syncthreads();
  if (threadIdx.x == 0)
    partial[blockIdx.x] = wps[0] + wps[1] + wps[2] + wps[3];
}

// ---- deterministic final loss reduction ----
__global__ void loss_kernel(const float* __restrict__ partial, int n,
                            float* __restrict__ out_loss) {
  double s = 0.0;
  for (int i = threadIdx.x; i < n; i += 256) s += (double)partial[i];
  __shared__ double sm[256];
  sm[threadIdx.x] = s;
  __syncthreads();
  for (int st = 128; st; st >>= 1) {
    if (threadIdx.x < st) sm[threadIdx.x] += sm[threadIdx.x + st];
    __syncthreads();
  }
  if (threadIdx.x == 0) {
    float loss = (float)(0.25 * sm[0] / (double)((size_t)NB * ND));
    out_loss[0] = loss;  // vq_loss
    out_loss[1] = loss;  // commitment loss (same forward value)
  }
}

}  // namespace

extern "C" void kernel_launch(void* const* d_in, const int* in_sizes, int n_in,
                              void* d_out, int out_size, void* d_ws, size_t ws_size,
                              hipStream_t stream) {
  const float* z = (const float*)d_in[0];
  const float* emb = (const float*)d_in[1];
  float* out = (float*)d_out;
  float* zq = out;
  float* loss = out + (size_t)NB * ND;
  float* idx_f = out + (size_t)NB * ND + 2;  // doubles as rowmax scratch

  unsigned short* ebf = (unsigned short*)d_ws;                      // 4 MB
  float* sz = (float*)((char*)d_ws + (size_t)NK * ND * 2);          // 128 KB
  float* partial = (float*)((char*)d_ws + (size_t)NK * ND * 2 + (size_t)NB * 4);

  sz_kernel<<<NB / 4, 256, 0, stream>>>(z, sz);
  ebf_kernel<<<NK * ND / 8 / 256, 256, 0, stream>>>(emb, ebf);
  mfma_scan<0><<<NB / 64, 256, 0, stream>>>(z, ebf, sz, idx_f, zq);
  mfma_scan<1><<<NB / 64, 256, 0, stream>>>(z, ebf, sz, idx_f, zq);
  exact_kernel<<<NB / 4, 256, 0, stream>>>(z, emb, sz, zq, idx_f, partial);
  loss_kernel<<<1, 256, 0, stream>>>(partial, NB / 4, loss);
}

// Round 20
// 4678.817 us; speedup vs baseline: 1.0002x; 1.0002x over previous
//
#include <hip/hip_runtime.h>

// VectorQuantizer: B=32768, K=8192, D=256, fp32.
// out layout (flat float): z_q [B*D], vq_loss [1], commit [1], indices-as-float [B]
// ws layout: ebf bf16[K*D] (4MB) | sz float[B] | partial float[B/4]
//
// Strategy (round 19): two-phase MFMA candidate filter + exact fp32 verify.
//  B1: bf16 MFMA GEMM-max -> rowmax of approx dot per row (written to idx_f slot).
//  B2: re-scan, emit codes with dot >= rowmax - M(row) into per-row buffer
//      (first 16 ints of the row's zq area).  M = 4e-5 + 3.2e-5*||z|| is 2x the
//      rigorous error bound (bf16 RNE rel-err 2^-9, ||e|| <= 16/8192, accum eps).
//  C:  exact fp32 FMA chain (ascending d, bit-identical to verified r2 numerics)
//      over candidates; first-index ties; fused gather/zq/loss. cnt>15 or ==0 ->
//      full exact scan fallback.
// MFMA fragments (16x16x32 bf16): A row=lane&15, k=(lane>>4)*8+i; B col=lane&15,
// same k map; C/D col=lane&15, row=(lane>>4)*4+reg [m89-verified family].

namespace {
constexpr int NB = 32768;
constexpr int NK = 8192;
constexpr int ND = 256;

typedef __attribute__((ext_vector_type(8))) short sh8;
typedef __attribute__((ext_vector_type(4))) float f32x4;

__device__ __forceinline__ unsigned short bf16_rne(float f) {
  unsigned int u = __float_as_uint(f);
  u += 0x7FFFu + ((u >> 16) & 1u);
  return (unsigned short)(u >> 16);
}

// ---- S[row] = ||z_row||^2 ----
__global__ void sz_kernel(const float* __restrict__ z, float* __restrict__ sz) {
  const int row = blockIdx.x * 4 + (threadIdx.x >> 6);
  const int lane = threadIdx.x & 63;
  const float4 v = reinterpret_cast<const float4*>(z)[(size_t)row * 64 + lane];
  float s = v.x * v.x + v.y * v.y + v.z * v.z + v.w * v.w;
#pragma unroll
  for (int off = 32; off; off >>= 1) s += __shfl_down(s, off, 64);
  if (lane == 0) sz[row] = s;
}

// ---- emb -> bf16 (RNE) ----
__global__ void ebf_kernel(const float* __restrict__ emb,
                           unsigned short* __restrict__ ebf) {
  const int i = blockIdx.x * 256 + threadIdx.x;  // 8 elems per thread
  const float4 a = reinterpret_cast<const float4*>(emb)[i * 2];
  const float4 b = reinterpret_cast<const float4*>(emb)[i * 2 + 1];
  uint4 o;
  o.x = (unsigned)bf16_rne(a.x) | ((unsigned)bf16_rne(a.y) << 16);
  o.y = (unsigned)bf16_rne(a.z) | ((unsigned)bf16_rne(a.w) << 16);
  o.z = (unsigned)bf16_rne(b.x) | ((unsigned)bf16_rne(b.y) << 16);
  o.w = (unsigned)bf16_rne(b.z) | ((unsigned)bf16_rne(b.w) << 16);
  reinterpret_cast<uint4*>(ebf)[i] = o;
}

// ---- MFMA scan: PASS 0 = rowmax, PASS 1 = candidate emission ----
template <int PASS>
__global__ __launch_bounds__(256, 1) void mfma_scan(
    const float* __restrict__ z, const unsigned short* __restrict__ ebf,
    const float* __restrict__ sz, float* __restrict__ rowmax,
    float* __restrict__ zqout) {
  const int lane = threadIdx.x & 63;
  const int w = threadIdx.x >> 6;
  const int r0 = blockIdx.x * 64 + w * 16;  // this wave's 16 rows
  const int cl = lane & 15;                 // A-row / B-col slot
  const int kg = lane >> 4;                 // k-group (0..3)

  // A fragments: rows r0+cl, k = q*32 + kg*8 + i  (bf16 on the fly)
  sh8 afrag[8];
  {
    const float* zp = z + (size_t)(r0 + cl) * ND + kg * 8;
#pragma unroll
    for (int q = 0; q < 8; ++q) {
      const float4 f0 = *reinterpret_cast<const float4*>(zp + q * 32);
      const float4 f1 = *reinterpret_cast<const float4*>(zp + q * 32 + 4);
      sh8 a;
      a[0] = (short)bf16_rne(f0.x); a[1] = (short)bf16_rne(f0.y);
      a[2] = (short)bf16_rne(f0.z); a[3] = (short)bf16_rne(f0.w);
      a[4] = (short)bf16_rne(f1.x); a[5] = (short)bf16_rne(f1.y);
      a[6] = (short)bf16_rne(f1.z); a[7] = (short)bf16_rne(f1.w);
      afrag[q] = a;
    }
  }

  float mx[4] = {-3.4e38f, -3.4e38f, -3.4e38f, -3.4e38f};
  float thr[4];
  if (PASS == 1) {
#pragma unroll
    for (int r = 0; r < 4; ++r) {
      const int row = r0 + kg * 4 + r;
      thr[r] = rowmax[row] - (4e-5f + 3.2e-5f * sqrtf(sz[row]));
    }
  }

  const unsigned short* bbase = ebf + kg * 8 + (size_t)cl * ND;
  auto loadB = [&](sh8* dst, int c0t) {
    const unsigned short* bp = bbase + (size_t)c0t * ND;
#pragma unroll
    for (int q = 0; q < 8; ++q)
      dst[q] = *reinterpret_cast<const sh8*>(bp + q * 32);
  };

  auto process = [&](const sh8* b, int t) {
    f32x4 c0 = {0.f, 0.f, 0.f, 0.f}, c1 = c0, c2 = c0, c3 = c0;
    c0 = __builtin_amdgcn_mfma_f32_16x16x32_bf16(afrag[0], b[0], c0, 0, 0, 0);
    c1 = __builtin_amdgcn_mfma_f32_16x16x32_bf16(afrag[1], b[1], c1, 0, 0, 0);
    c2 = __builtin_amdgcn_mfma_f32_16x16x32_bf16(afrag[2], b[2], c2, 0, 0, 0);
    c3 = __builtin_amdgcn_mfma_f32_16x16x32_bf16(afrag[3], b[3], c3, 0, 0, 0);
    c0 = __builtin_amdgcn_mfma_f32_16x16x32_bf16(afrag[4], b[4], c0, 0, 0, 0);
    c1 = __builtin_amdgcn_mfma_f32_16x16x32_bf16(afrag[5], b[5], c1, 0, 0, 0);
    c2 = __builtin_amdgcn_mfma_f32_16x16x32_bf16(afrag[6], b[6], c2, 0, 0, 0);
    c3 = __builtin_amdgcn_mfma_f32_16x16x32_bf16(afrag[7], b[7], c3, 0, 0, 0);
    const f32x4 dot = (c0 + c1) + (c2 + c3);
    if (PASS == 0) {
#pragma unroll
      for (int r = 0; r < 4; ++r) mx[r] = fmaxf(mx[r], dot[r]);
    } else {
#pragma unroll
      for (int r = 0; r < 4; ++r) {
        if (dot[r] >= thr[r]) {
          const int row = r0 + kg * 4 + r;
          const int code = t * 16 + cl;
          int* cp = (int*)(zqout + (size_t)row * ND);
          const int slot = atomicAdd(cp, 1);
          if (slot < 15) cp[1 + slot] = code;
        }
      }
    }
  };

  sh8 bA[8], bB[8];
  loadB(bA, 0);
  for (int t = 0; t < NK / 16; t += 2) {  // 512 tiles, ping-pong unrolled
    loadB(bB, (t + 1) * 16);
    process(bA, t);
    if (t + 2 < NK / 16) loadB(bA, (t + 2) * 16);
    process(bB, t + 1);
  }

  if (PASS == 0) {
    // reduce max across the 16 col-lanes of each kg group
#pragma unroll
    for (int r = 0; r < 4; ++r) {
      float v = mx[r];
#pragma unroll
      for (int m = 1; m < 16; m <<= 1) v = fmaxf(v, __shfl_xor(v, m, 64));
      if (cl == 0) rowmax[r0 + kg * 4 + r] = v;
    }
    // zero candidate counters for this block's 64 rows
    if (threadIdx.x < 64)
      ((int*)(zqout + (size_t)(blockIdx.x * 64 + threadIdx.x) * ND))[0] = 0;
  }
}

// ---- exact verify + gather + loss partial (4 rows per block) ----
__global__ __launch_bounds__(256, 1) void exact_kernel(
    const float* __restrict__ z, const float* __restrict__ emb,
    const float* __restrict__ sz, float* __restrict__ zq,
    float* __restrict__ idx_f, float* __restrict__ partial) {
  __shared__ float wps[4];
  const int lane = threadIdx.x & 63;
  const int w = threadIdx.x >> 6;
  const int row = blockIdx.x * 4 + w;
  int* cp = (int*)(zq + (size_t)row * ND);
  const int cnt = cp[0];
  const float S = sz[row];
  const float4* zp = reinterpret_cast<const float4*>(z + (size_t)row * ND);

  float bd = 3.4e38f;
  int bc = 0x7fffffff;
  if (cnt >= 1 && cnt <= 15) {
    if (lane < cnt) {
      const int k = cp[1 + lane];
      const float4* ep = reinterpret_cast<const float4*>(emb + (size_t)k * ND);
      float acc = 0.f;
#pragma unroll 8
      for (int q = 0; q < 64; ++q) {  // exact chain, ascending d
        const float4 zz = zp[q];
        const float4 ee = ep[q];
        acc = fmaf(zz.x, ee.x, acc);
        acc = fmaf(zz.y, ee.y, acc);
        acc = fmaf(zz.z, ee.z, acc);
        acc = fmaf(zz.w, ee.w, acc);
      }
      bd = fmaf(-2.f, acc, S);
      bc = k;
    }
  } else {
    // fallback: full exact scan (overflow or empty — correctness net)
    for (int code = lane; code < NK; code += 64) {
      const float4* ep = reinterpret_cast<const float4*>(emb + (size_t)code * ND);
      float acc = 0.f;
#pragma unroll 8
      for (int q = 0; q < 64; ++q) {
        const float4 zz = zp[q];
        const float4 ee = ep[q];
        acc = fmaf(zz.x, ee.x, acc);
        acc = fmaf(zz.y, ee.y, acc);
        acc = fmaf(zz.z, ee.z, acc);
        acc = fmaf(zz.w, ee.w, acc);
      }
      const float dist = fmaf(-2.f, acc, S);
      if (dist < bd || (dist == bd && code < bc)) { bd = dist; bc = code; }
    }
  }
  // min-reduce across 64 lanes; lowest code on exact ties
#pragma unroll
  for (int m = 1; m < 64; m <<= 1) {
    const float od = __shfl_xor(bd, m, 64);
    const int oc = __shfl_xor(bc, m, 64);
    if (od < bd || (od == bd && oc < bc)) { bd = od; bc = oc; }
  }
  // fused gather (reads of cp finished above; safe to overwrite)
  const float4 e = reinterpret_cast<const float4*>(emb)[(size_t)bc * 64 + lane];
  const float4 zv = zp[lane];
  reinterpret_cast<float4*>(zq)[(size_t)row * 64 + lane] = e;
  const float dx = e.x - zv.x, dy = e.y - zv.y;
  const float dz = e.z - zv.z, dw = e.w - zv.w;
  float s = dx * dx + dy * dy + dz * dz + dw * dw;
#pragma unroll
  for (int off = 32; off; off >>= 1) s += __shfl_down(s, off, 64);
  if (lane == 0) {
    idx_f[row] = (float)bc;
    wps[w] = s;
  }
  __syncthreads();
  if (threadIdx.x == 0)
    partial[blockIdx.x] = wps[0] + wps[1] + wps[2] + wps[3];
}

// ---- deterministic final loss reduction ----
__global__ void loss_kernel(const float* __restrict__ partial, int n,
                            float* __restrict__ out_loss) {
  double s = 0.0;
  for (int i = threadIdx.x; i < n; i += 256) s += (double)partial[i];
  __shared__ double sm[256];
  sm[threadIdx.x] = s;
  __syncthreads();
  for (int st = 128; st; st >>= 1) {
    if (threadIdx.x < st) sm[threadIdx.x] += sm[threadIdx.x + st];
    __syncthreads();
  }
  if (threadIdx.x == 0) {
    float loss = (float)(0.25 * sm[0] / (double)((size_t)NB * ND));
    out_loss[0] = loss;  // vq_loss
    out_loss[1] = loss;  // commitment loss (same forward value)
  }
}

}  // namespace

extern "C" void kernel_launch(void* const* d_in, const int* in_sizes, int n_in,
                              void* d_out, int out_size, void* d_ws, size_t ws_size,
                              hipStream_t stream) {
  const float* z = (const float*)d_in[0];
  const float* emb = (const float*)d_in[1];
  float* out = (float*)d_out;
  float* zq = out;
  float* loss = out + (size_t)NB * ND;
  float* idx_f = out + (size_t)NB * ND + 2;  // doubles as rowmax scratch

  unsigned short* ebf = (unsigned short*)d_ws;                      // 4 MB
  float* sz = (float*)((char*)d_ws + (size_t)NK * ND * 2);          // 128 KB
  float* partial = (float*)((char*)d_ws + (size_t)NK * ND * 2 + (size_t)NB * 4);

  sz_kernel<<<NB / 4, 256, 0, stream>>>(z, sz);
  ebf_kernel<<<NK * ND / 8 / 256, 256, 0, stream>>>(emb, ebf);
  mfma_scan<0><<<NB / 64, 256, 0, stream>>>(z, ebf, sz, idx_f, zq);
  mfma_scan<1><<<NB / 64, 256, 0, stream>>>(z, ebf, sz, idx_f, zq);
  exact_kernel<<<NB / 4, 256, 0, stream>>>(z, emb, sz, zq, idx_f, partial);
  loss_kernel<<<1, 256, 0, stream>>>(partial, NB / 4, loss);
}

// Round 21
// 1210.982 us; speedup vs baseline: 3.8643x; 3.8637x over previous
//
#include <hip/hip_runtime.h>

// VectorQuantizer: B=32768, K=8192, D=256, fp32.
// out layout (flat float): z_q [B*D], vq_loss [1], commit [1], indices-as-float [B]
// ws layout: ebf bf16[K*D] (4MB) | sz float[B] | partial float[B/4]
//
// Strategy (r19-r21): MFMA candidate filter + exact fp32 verify.
//  scan (single sweep): bf16 MFMA dots; per-lane running max with 16-lane
//    sync every 8 tiles; emit codes with dot >= runmax - M into per-row
//    buffer (255 slots in the row's zq area). Superset of the exact-window
//    set since runmax <= final max. M = 4e-5 + 3.2e-5*||z|| = 2x rigorous
//    bf16 error bound (rel 2^-8 on sum|z_i e_i| <= ||z||*16/8192, + accum).
//  exact: fp32 FMA chain (ascending d, bit-identical to verified r2
//    numerics) over candidates; first-index ties; fused gather/zq/loss.
//    cnt==0 or >255 -> full exact scan fallback (correctness net, ~never).
// MFMA fragments (16x16x32 bf16, validated r20): A row=lane&15,
// k=(lane>>4)*8+i; B col=lane&15 same k; C/D col=lane&15, row=(lane>>4)*4+reg.

namespace {
constexpr int NB = 32768;
constexpr int NK = 8192;
constexpr int ND = 256;

typedef __attribute__((ext_vector_type(8))) short sh8;
typedef __attribute__((ext_vector_type(4))) float f32x4;

__device__ __forceinline__ unsigned short bf16_rne(float f) {
  unsigned int u = __float_as_uint(f);
  u += 0x7FFFu + ((u >> 16) & 1u);
  return (unsigned short)(u >> 16);
}

// ---- S[row] = ||z_row||^2 ----
__global__ void sz_kernel(const float* __restrict__ z, float* __restrict__ sz) {
  const int row = blockIdx.x * 4 + (threadIdx.x >> 6);
  const int lane = threadIdx.x & 63;
  const float4 v = reinterpret_cast<const float4*>(z)[(size_t)row * 64 + lane];
  float s = v.x * v.x + v.y * v.y + v.z * v.z + v.w * v.w;
#pragma unroll
  for (int off = 32; off; off >>= 1) s += __shfl_down(s, off, 64);
  if (lane == 0) sz[row] = s;
}

// ---- emb -> bf16 (RNE) ----
__global__ void ebf_kernel(const float* __restrict__ emb,
                           unsigned short* __restrict__ ebf) {
  const int i = blockIdx.x * 256 + threadIdx.x;  // 8 elems per thread
  const float4 a = reinterpret_cast<const float4*>(emb)[i * 2];
  const float4 b = reinterpret_cast<const float4*>(emb)[i * 2 + 1];
  uint4 o;
  o.x = (unsigned)bf16_rne(a.x) | ((unsigned)bf16_rne(a.y) << 16);
  o.y = (unsigned)bf16_rne(a.z) | ((unsigned)bf16_rne(a.w) << 16);
  o.z = (unsigned)bf16_rne(b.x) | ((unsigned)bf16_rne(b.y) << 16);
  o.w = (unsigned)bf16_rne(b.z) | ((unsigned)bf16_rne(b.w) << 16);
  reinterpret_cast<uint4*>(ebf)[i] = o;
}

// ---- single-sweep MFMA scan with inline candidate emission ----
__global__ __launch_bounds__(256, 1) void mfma_scan(
    const float* __restrict__ z, const unsigned short* __restrict__ ebf,
    const float* __restrict__ sz, float* __restrict__ zqout) {
  const int lane = threadIdx.x & 63;
  const int w = threadIdx.x >> 6;
  const int r0 = blockIdx.x * 64 + w * 16;  // this wave's 16 rows
  const int cl = lane & 15;                 // A-row / B-col slot
  const int kg = lane >> 4;                 // k-group (0..3)

  // zero candidate counters for this wave's 16 rows (only this wave emits)
  if (lane < 16) ((int*)(zqout + (size_t)(r0 + lane) * ND))[0] = 0;
  __syncthreads();  // drains vmem -> zeros visible before any atomicAdd

  // A fragments: rows r0+cl, k = q*32 + kg*8 + i  (bf16 on the fly)
  sh8 afrag[8];
  {
    const float* zp = z + (size_t)(r0 + cl) * ND + kg * 8;
#pragma unroll
    for (int q = 0; q < 8; ++q) {
      const float4 f0 = *reinterpret_cast<const float4*>(zp + q * 32);
      const float4 f1 = *reinterpret_cast<const float4*>(zp + q * 32 + 4);
      sh8 a;
      a[0] = (short)bf16_rne(f0.x); a[1] = (short)bf16_rne(f0.y);
      a[2] = (short)bf16_rne(f0.z); a[3] = (short)bf16_rne(f0.w);
      a[4] = (short)bf16_rne(f1.x); a[5] = (short)bf16_rne(f1.y);
      a[6] = (short)bf16_rne(f1.z); a[7] = (short)bf16_rne(f1.w);
      afrag[q] = a;
    }
  }

  // per-lane rows r = r0 + kg*4 + (0..3): margin + candidate buffers
  float M[4];
  int* cpb[4];
#pragma unroll
  for (int r = 0; r < 4; ++r) {
    const int row = r0 + kg * 4 + r;
    M[r] = 4e-5f + 3.2e-5f * sqrtf(sz[row]);
    cpb[r] = (int*)(zqout + (size_t)row * ND);
  }

  const unsigned short* bbase = ebf + kg * 8 + (size_t)cl * ND;
  auto loadB = [&](sh8* dst, int c0t) {
    const unsigned short* bp = bbase + (size_t)c0t * ND;
#pragma unroll
    for (int q = 0; q < 8; ++q)
      dst[q] = *reinterpret_cast<const sh8*>(bp + q * 32);
  };

  auto dotTile = [&](const sh8* b) -> f32x4 {
    f32x4 c0 = {0.f, 0.f, 0.f, 0.f}, c1 = c0, c2 = c0, c3 = c0;
    c0 = __builtin_amdgcn_mfma_f32_16x16x32_bf16(afrag[0], b[0], c0, 0, 0, 0);
    c1 = __builtin_amdgcn_mfma_f32_16x16x32_bf16(afrag[1], b[1], c1, 0, 0, 0);
    c2 = __builtin_amdgcn_mfma_f32_16x16x32_bf16(afrag[2], b[2], c2, 0, 0, 0);
    c3 = __builtin_amdgcn_mfma_f32_16x16x32_bf16(afrag[3], b[3], c3, 0, 0, 0);
    c0 = __builtin_amdgcn_mfma_f32_16x16x32_bf16(afrag[4], b[4], c0, 0, 0, 0);
    c1 = __builtin_amdgcn_mfma_f32_16x16x32_bf16(afrag[5], b[5], c1, 0, 0, 0);
    c2 = __builtin_amdgcn_mfma_f32_16x16x32_bf16(afrag[6], b[6], c2, 0, 0, 0);
    c3 = __builtin_amdgcn_mfma_f32_16x16x32_bf16(afrag[7], b[7], c3, 0, 0, 0);
    return (c0 + c1) + (c2 + c3);
  };

  float runmax[4];
  auto syncmax = [&]() {
#pragma unroll
    for (int r = 0; r < 4; ++r) {
      float v = runmax[r];
#pragma unroll
      for (int m = 1; m < 16; m <<= 1) v = fmaxf(v, __shfl_xor(v, m, 64));
      runmax[r] = v;
    }
  };

  sh8 bA[8], bB[8];
  loadB(bA, 0);
  {  // bootstrap: tile 0 initializes runmax (no emission)
    const f32x4 d0 = dotTile(bA);
#pragma unroll
    for (int r = 0; r < 4; ++r) runmax[r] = d0[r];
    syncmax();
  }

  auto emitproc = [&](const sh8* b, int t) {
    const f32x4 dot = dotTile(b);
#pragma unroll
    for (int r = 0; r < 4; ++r) {
      if (dot[r] >= runmax[r] - M[r]) {
        const int slot = atomicAdd(cpb[r], 1);
        if (slot < 255) cpb[r][1 + slot] = t * 16 + cl;
      }
      runmax[r] = fmaxf(runmax[r], dot[r]);
    }
  };

  for (int t = 0; t < NK / 16; t += 2) {  // 512 tiles, ping-pong
    loadB(bB, (t + 1) * 16);
    emitproc(bA, t);
    if (t + 2 < NK / 16) loadB(bA, (t + 2) * 16);
    emitproc(bB, t + 1);
    if ((t & 6) == 6) syncmax();  // every 8 tiles: bound running-max lag
  }
}

// ---- exact verify + gather + loss partial (4 rows per block) ----
__global__ __launch_bounds__(256, 1) void exact_kernel(
    const float* __restrict__ z, const float* __restrict__ emb,
    const float* __restrict__ sz, float* __restrict__ zq,
    float* __restrict__ idx_f, float* __restrict__ partial) {
  __shared__ float wps[4];
  const int lane = threadIdx.x & 63;
  const int w = threadIdx.x >> 6;
  const int row = blockIdx.x * 4 + w;
  int* cp = (int*)(zq + (size_t)row * ND);
  const int cnt = cp[0];
  const float S = sz[row];
  const float4* zp = reinterpret_cast<const float4*>(z + (size_t)row * ND);

  float bd = 3.4e38f;
  int bc = 0x7fffffff;
  if (cnt >= 1 && cnt <= 255) {
    for (int c = lane; c < cnt; c += 64) {
      const int k = cp[1 + c];
      const float4* ep = reinterpret_cast<const float4*>(emb + (size_t)k * ND);
      float acc = 0.f;
#pragma unroll 8
      for (int q = 0; q < 64; ++q) {  // exact chain, ascending d
        const float4 zz = zp[q];
        const float4 ee = ep[q];
        acc = fmaf(zz.x, ee.x, acc);
        acc = fmaf(zz.y, ee.y, acc);
        acc = fmaf(zz.z, ee.z, acc);
        acc = fmaf(zz.w, ee.w, acc);
      }
      const float dist = fmaf(-2.f, acc, S);
      if (dist < bd || (dist == bd && k < bc)) { bd = dist; bc = k; }
    }
  } else {
    // fallback: full exact scan (overflow/empty — correctness net, ~never)
    for (int code = lane; code < NK; code += 64) {
      const float4* ep = reinterpret_cast<const float4*>(emb + (size_t)code * ND);
      float acc = 0.f;
#pragma unroll 8
      for (int q = 0; q < 64; ++q) {
        const float4 zz = zp[q];
        const float4 ee = ep[q];
        acc = fmaf(zz.x, ee.x, acc);
        acc = fmaf(zz.y, ee.y, acc);
        acc = fmaf(zz.z, ee.z, acc);
        acc = fmaf(zz.w, ee.w, acc);
      }
      const float dist = fmaf(-2.f, acc, S);
      if (dist < bd || (dist == bd && code < bc)) { bd = dist; bc = code; }
    }
  }
  // min-reduce across 64 lanes; lowest code on exact ties
#pragma unroll
  for (int m = 1; m < 64; m <<= 1) {
    const float od = __shfl_xor(bd, m, 64);
    const int oc = __shfl_xor(bc, m, 64);
    if (od < bd || (od == bd && oc < bc)) { bd = od; bc = oc; }
  }
  // fused gather (candidate reads finished; safe to overwrite zq row)
  const float4 e = reinterpret_cast<const float4*>(emb)[(size_t)bc * 64 + lane];
  const float4 zv = zp[lane];
  reinterpret_cast<float4*>(zq)[(size_t)row * 64 + lane] = e;
  const float dx = e.x - zv.x, dy = e.y - zv.y;
  const float dz = e.z - zv.z, dw = e.w - zv.w;
  float s = dx * dx + dy * dy + dz * dz + dw * dw;
#pragma unroll
  for (int off = 32; off; off >>= 1) s += __shfl_down(s, off, 64);
  if (lane == 0) {
    idx_f[row] = (float)bc;
    wps[w] = s;
  }
  __syncthreads();
  if (threadIdx.x == 0)
    partial[blockIdx.x] = wps[0] + wps[1] + wps[2] + wps[3];
}

// ---- deterministic final loss reduction ----
__global__ void loss_kernel(const float* __restrict__ partial, int n,
                            float* __restrict__ out_loss) {
  double s = 0.0;
  for (int i = threadIdx.x; i < n; i += 256) s += (double)partial[i];
  __shared__ double sm[256];
  sm[threadIdx.x] = s;
  __syncthreads();
  for (int st = 128; st; st >>= 1) {
    if (threadIdx.x < st) sm[threadIdx.x] += sm[threadIdx.x + st];
    __syncthreads();
  }
  if (threadIdx.x == 0) {
    float loss = (float)(0.25 * sm[0] / (double)((size_t)NB * ND));
    out_loss[0] = loss;  // vq_loss
    out_loss[1] = loss;  // commitment loss (same forward value)
  }
}

}  // namespace

extern "C" void kernel_launch(void* const* d_in, const int* in_sizes, int n_in,
                              void* d_out, int out_size, void* d_ws, size_t ws_size,
                              hipStream_t stream) {
  const float* z = (const float*)d_in[0];
  const float* emb = (const float*)d_in[1];
  float* out = (float*)d_out;
  float* zq = out;
  float* loss = out + (size_t)NB * ND;
  float* idx_f = out + (size_t)NB * ND + 2;

  unsigned short* ebf = (unsigned short*)d_ws;                      // 4 MB
  float* sz = (float*)((char*)d_ws + (size_t)NK * ND * 2);          // 128 KB
  float* partial = (float*)((char*)d_ws + (size_t)NK * ND * 2 + (size_t)NB * 4);

  sz_kernel<<<NB / 4, 256, 0, stream>>>(z, sz);
  ebf_kernel<<<NK * ND / 8 / 256, 256, 0, stream>>>(emb, ebf);
  mfma_scan<<<NB / 64, 256, 0, stream>>>(z, ebf, sz, zq);
  exact_kernel<<<NB / 4, 256, 0, stream>>>(z, emb, sz, zq, idx_f, partial);
  loss_kernel<<<1, 256, 0, stream>>>(partial, NB / 4, loss);
}

// Round 22
// 1209.864 us; speedup vs baseline: 3.8679x; 1.0009x over previous
//
#include <hip/hip_runtime.h>

// VectorQuantizer: B=32768, K=8192, D=256, fp32.
// out layout (flat float): z_q [B*D], vq_loss [1], commit [1], indices-as-float [B]
// ws layout: ebf bf16[K*D] (4MB) | sz float[B] | partial float[B/4]
//
// Strategy (r19-r21): MFMA candidate filter + exact fp32 verify.
//  scan (single sweep): bf16 MFMA dots; per-lane running max with 16-lane
//    sync every 8 tiles; emit codes with dot >= runmax - M into per-row
//    buffer (255 slots in the row's zq area). Superset of the exact-window
//    set since runmax <= final max. M = 4e-5 + 3.2e-5*||z|| = 2x rigorous
//    bf16 error bound (rel 2^-8 on sum|z_i e_i| <= ||z||*16/8192, + accum).
//  exact: fp32 FMA chain (ascending d, bit-identical to verified r2
//    numerics) over candidates; first-index ties; fused gather/zq/loss.
//    cnt==0 or >255 -> full exact scan fallback (correctness net, ~never).
// MFMA fragments (16x16x32 bf16, validated r20): A row=lane&15,
// k=(lane>>4)*8+i; B col=lane&15 same k; C/D col=lane&15, row=(lane>>4)*4+reg.

namespace {
constexpr int NB = 32768;
constexpr int NK = 8192;
constexpr int ND = 256;

typedef __attribute__((ext_vector_type(8))) short sh8;
typedef __attribute__((ext_vector_type(4))) float f32x4;

__device__ __forceinline__ unsigned short bf16_rne(float f) {
  unsigned int u = __float_as_uint(f);
  u += 0x7FFFu + ((u >> 16) & 1u);
  return (unsigned short)(u >> 16);
}

// ---- S[row] = ||z_row||^2 ----
__global__ void sz_kernel(const float* __restrict__ z, float* __restrict__ sz) {
  const int row = blockIdx.x * 4 + (threadIdx.x >> 6);
  const int lane = threadIdx.x & 63;
  const float4 v = reinterpret_cast<const float4*>(z)[(size_t)row * 64 + lane];
  float s = v.x * v.x + v.y * v.y + v.z * v.z + v.w * v.w;
#pragma unroll
  for (int off = 32; off; off >>= 1) s += __shfl_down(s, off, 64);
  if (lane == 0) sz[row] = s;
}

// ---- emb -> bf16 (RNE) ----
__global__ void ebf_kernel(const float* __restrict__ emb,
                           unsigned short* __restrict__ ebf) {
  const int i = blockIdx.x * 256 + threadIdx.x;  // 8 elems per thread
  const float4 a = reinterpret_cast<const float4*>(emb)[i * 2];
  const float4 b = reinterpret_cast<const float4*>(emb)[i * 2 + 1];
  uint4 o;
  o.x = (unsigned)bf16_rne(a.x) | ((unsigned)bf16_rne(a.y) << 16);
  o.y = (unsigned)bf16_rne(a.z) | ((unsigned)bf16_rne(a.w) << 16);
  o.z = (unsigned)bf16_rne(b.x) | ((unsigned)bf16_rne(b.y) << 16);
  o.w = (unsigned)bf16_rne(b.z) | ((unsigned)bf16_rne(b.w) << 16);
  reinterpret_cast<uint4*>(ebf)[i] = o;
}

// ---- single-sweep MFMA scan with inline candidate emission ----
__global__ __launch_bounds__(256, 1) void mfma_scan(
    const float* __restrict__ z, const unsigned short* __restrict__ ebf,
    const float* __restrict__ sz, float* __restrict__ zqout) {
  const int lane = threadIdx.x & 63;
  const int w = threadIdx.x >> 6;
  const int r0 = blockIdx.x * 64 + w * 16;  // this wave's 16 rows
  const int cl = lane & 15;                 // A-row / B-col slot
  const int kg = lane >> 4;                 // k-group (0..3)

  // zero candidate counters for this wave's 16 rows (only this wave emits)
  if (lane < 16) ((int*)(zqout + (size_t)(r0 + lane) * ND))[0] = 0;
  __syncthreads();  // drains vmem -> zeros visible before any atomicAdd

  // A fragments: rows r0+cl, k = q*32 + kg*8 + i  (bf16 on the fly)
  sh8 afrag[8];
  {
    const float* zp = z + (size_t)(r0 + cl) * ND + kg * 8;
#pragma unroll
    for (int q = 0; q < 8; ++q) {
      const float4 f0 = *reinterpret_cast<const float4*>(zp + q * 32);
      const float4 f1 = *reinterpret_cast<const float4*>(zp + q * 32 + 4);
      sh8 a;
      a[0] = (short)bf16_rne(f0.x); a[1] = (short)bf16_rne(f0.y);
      a[2] = (short)bf16_rne(f0.z); a[3] = (short)bf16_rne(f0.w);
      a[4] = (short)bf16_rne(f1.x); a[5] = (short)bf16_rne(f1.y);
      a[6] = (short)bf16_rne(f1.z); a[7] = (short)bf16_rne(f1.w);
      afrag[q] = a;
    }
  }

  // per-lane rows r = r0 + kg*4 + (0..3): margin + candidate buffers
  float M[4];
  int* cpb[4];
#pragma unroll
  for (int r = 0; r < 4; ++r) {
    const int row = r0 + kg * 4 + r;
    M[r] = 4e-5f + 3.2e-5f * sqrtf(sz[row]);
    cpb[r] = (int*)(zqout + (size_t)row * ND);
  }

  const unsigned short* bbase = ebf + kg * 8 + (size_t)cl * ND;
  auto loadB = [&](sh8* dst, int c0t) {
    const unsigned short* bp = bbase + (size_t)c0t * ND;
#pragma unroll
    for (int q = 0; q < 8; ++q)
      dst[q] = *reinterpret_cast<const sh8*>(bp + q * 32);
  };

  auto dotTile = [&](const sh8* b) -> f32x4 {
    f32x4 c0 = {0.f, 0.f, 0.f, 0.f}, c1 = c0, c2 = c0, c3 = c0;
    c0 = __builtin_amdgcn_mfma_f32_16x16x32_bf16(afrag[0], b[0], c0, 0, 0, 0);
    c1 = __builtin_amdgcn_mfma_f32_16x16x32_bf16(afrag[1], b[1], c1, 0, 0, 0);
    c2 = __builtin_amdgcn_mfma_f32_16x16x32_bf16(afrag[2], b[2], c2, 0, 0, 0);
    c3 = __builtin_amdgcn_mfma_f32_16x16x32_bf16(afrag[3], b[3], c3, 0, 0, 0);
    c0 = __builtin_amdgcn_mfma_f32_16x16x32_bf16(afrag[4], b[4], c0, 0, 0, 0);
    c1 = __builtin_amdgcn_mfma_f32_16x16x32_bf16(afrag[5], b[5], c1, 0, 0, 0);
    c2 = __builtin_amdgcn_mfma_f32_16x16x32_bf16(afrag[6], b[6], c2, 0, 0, 0);
    c3 = __builtin_amdgcn_mfma_f32_16x16x32_bf16(afrag[7], b[7], c3, 0, 0, 0);
    return (c0 + c1) + (c2 + c3);
  };

  float runmax[4];
  auto syncmax = [&]() {
#pragma unroll
    for (int r = 0; r < 4; ++r) {
      float v = runmax[r];
#pragma unroll
      for (int m = 1; m < 16; m <<= 1) v = fmaxf(v, __shfl_xor(v, m, 64));
      runmax[r] = v;
    }
  };

  sh8 bA[8], bB[8];
  loadB(bA, 0);
  {  // bootstrap: tile 0 initializes runmax (no emission)
    const f32x4 d0 = dotTile(bA);
#pragma unroll
    for (int r = 0; r < 4; ++r) runmax[r] = d0[r];
    syncmax();
  }

  auto emitproc = [&](const sh8* b, int t) {
    const f32x4 dot = dotTile(b);
#pragma unroll
    for (int r = 0; r < 4; ++r) {
      if (dot[r] >= runmax[r] - M[r]) {
        const int slot = atomicAdd(cpb[r], 1);
        if (slot < 255) cpb[r][1 + slot] = t * 16 + cl;
      }
      runmax[r] = fmaxf(runmax[r], dot[r]);
    }
  };

  for (int t = 0; t < NK / 16; t += 2) {  // 512 tiles, ping-pong
    loadB(bB, (t + 1) * 16);
    emitproc(bA, t);
    if (t + 2 < NK / 16) loadB(bA, (t + 2) * 16);
    emitproc(bB, t + 1);
    if ((t & 6) == 6) syncmax();  // every 8 tiles: bound running-max lag
  }
}

// ---- exact verify + gather + loss partial (4 rows per block) ----
__global__ __launch_bounds__(256, 1) void exact_kernel(
    const float* __restrict__ z, const float* __restrict__ emb,
    const float* __restrict__ sz, float* __restrict__ zq,
    float* __restrict__ idx_f, float* __restrict__ partial) {
  __shared__ float wps[4];
  const int lane = threadIdx.x & 63;
  const int w = threadIdx.x >> 6;
  const int row = blockIdx.x * 4 + w;
  int* cp = (int*)(zq + (size_t)row * ND);
  const int cnt = cp[0];
  const float S = sz[row];
  const float4* zp = reinterpret_cast<const float4*>(z + (size_t)row * ND);

  float bd = 3.4e38f;
  int bc = 0x7fffffff;
  if (cnt >= 1 && cnt <= 255) {
    for (int c = lane; c < cnt; c += 64) {
      const int k = cp[1 + c];
      const float4* ep = reinterpret_cast<const float4*>(emb + (size_t)k * ND);
      float acc = 0.f;
#pragma unroll 8
      for (int q = 0; q < 64; ++q) {  // exact chain, ascending d
        const float4 zz = zp[q];
        const float4 ee = ep[q];
        acc = fmaf(zz.x, ee.x, acc);
        acc = fmaf(zz.y, ee.y, acc);
        acc = fmaf(zz.z, ee.z, acc);
        acc = fmaf(zz.w, ee.w, acc);
      }
      const float dist = fmaf(-2.f, acc, S);
      if (dist < bd || (dist == bd && k < bc)) { bd = dist; bc = k; }
    }
  } else {
    // fallback: full exact scan (overflow/empty — correctness net, ~never)
    for (int code = lane; code < NK; code += 64) {
      const float4* ep = reinterpret_cast<const float4*>(emb + (size_t)code * ND);
      float acc = 0.f;
#pragma unroll 8
      for (int q = 0; q < 64; ++q) {
        const float4 zz = zp[q];
        const float4 ee = ep[q];
        acc = fmaf(zz.x, ee.x, acc);
        acc = fmaf(zz.y, ee.y, acc);
        acc = fmaf(zz.z, ee.z, acc);
        acc = fmaf(zz.w, ee.w, acc);
      }
      const float dist = fmaf(-2.f, acc, S);
      if (dist < bd || (dist == bd && code < bc)) { bd = dist; bc = code; }
    }
  }
  // min-reduce across 64 lanes; lowest code on exact ties
#pragma unroll
  for (int m = 1; m < 64; m <<= 1) {
    const float od = __shfl_xor(bd, m, 64);
    const int oc = __shfl_xor(bc, m, 64);
    if (od < bd || (od == bd && oc < bc)) { bd = od; bc = oc; }
  }
  // fused gather (candidate reads finished; safe to overwrite zq row)
  const float4 e = reinterpret_cast<const float4*>(emb)[(size_t)bc * 64 + lane];
  const float4 zv = zp[lane];
  reinterpret_cast<float4*>(zq)[(size_t)row * 64 + lane] = e;
  const float dx = e.x - zv.x, dy = e.y - zv.y;
  const float dz = e.z - zv.z, dw = e.w - zv.w;
  float s = dx * dx + dy * dy + dz * dz + dw * dw;
#pragma unroll
  for (int off = 32; off; off >>= 1) s += __shfl_down(s, off, 64);
  if (lane == 0) {
    idx_f[row] = (float)bc;
    wps[w] = s;
  }
  __syncthreads();
  if (threadIdx.x == 0)
    partial[blockIdx.x] = wps[0] + wps[1] + wps[2] + wps[3];
}

// ---- deterministic final loss reduction ----
__global__ void loss_kernel(const float* __restrict__ partial, int n,
                            float* __restrict__ out_loss) {
  double s = 0.0;
  for (int i = threadIdx.x; i < n; i += 256) s += (double)partial[i];
  __shared__ double sm[256];
  sm[threadIdx.x] = s;
  __syncthreads();
  for (int st = 128; st; st >>= 1) {
    if (threadIdx.x < st) sm[threadIdx.x] += sm[threadIdx.x + st];
    __syncthreads();
  }
  if (threadIdx.x == 0) {
    float loss = (float)(0.25 * sm[0] / (double)((size_t)NB * ND));
    out_loss[0] = loss;  // vq_loss
    out_loss[1] = loss;  // commitment loss (same forward value)
  }
}

}  // namespace

extern "C" void kernel_launch(void* const* d_in, const int* in_sizes, int n_in,
                              void* d_out, int out_size, void* d_ws, size_t ws_size,
                              hipStream_t stream) {
  const float* z = (const float*)d_in[0];
  const float* emb = (const float*)d_in[1];
  float* out = (float*)d_out;
  float* zq = out;
  float* loss = out + (size_t)NB * ND;
  float* idx_f = out + (size_t)NB * ND + 2;

  unsigned short* ebf = (unsigned short*)d_ws;                      // 4 MB
  float* sz = (float*)((char*)d_ws + (size_t)NK * ND * 2);          // 128 KB
  float* partial = (float*)((char*)d_ws + (size_t)NK * ND * 2 + (size_t)NB * 4);

  sz_kernel<<<NB / 4, 256, 0, stream>>>(z, sz);
  ebf_kernel<<<NK * ND / 8 / 256, 256, 0, stream>>>(emb, ebf);
  mfma_scan<<<NB / 64, 256, 0, stream>>>(z, ebf, sz, zq);
  exact_kernel<<<NB / 4, 256, 0, stream>>>(z, emb, sz, zq, idx_f, partial);
  loss_kernel<<<1, 256, 0, stream>>>(partial, NB / 4, loss);
}